// Round 4
// baseline (7703.505 us; speedup 1.0000x reference)
//
#include <hip/hip_runtime.h>
#include <hip/hip_bf16.h>

// DecoderRNNsearch on MI355X — round 4: persistent-loop kernel.
// The 64-step recurrence runs inside ONE 256-block kernel with 2 device-scope
// grid barriers per step (agent-scope atomics). Blocks stay CU-pinned, so
// per-step operand slices (Whh hi/lo planes, ctxW rows) become XCD-L2-hot.
// Prologue GEMMs unchanged except ctxW is folded into the ctxWc GEMM
// (C buffer 4096x4096: cols 0..3071 = ctxWc, cols 3072..4095 = ctxW).
// All 3H-dim data row-permuted j' = 3u+g (u=hidden unit, g=r/z/n gate).
// Precision: sequential path effective-fp32 (split-bf16 3-pass products).

using short8 = __attribute__((ext_vector_type(8))) short;
using f32x4  = __attribute__((ext_vector_type(4))) float;

#define FLAG_ACC 1
#define FLAG_BF  2
#define NBLK 256

__device__ __forceinline__ void gld16(const void* g, void* l) {
  __builtin_amdgcn_global_load_lds(
      (const __attribute__((address_space(1))) unsigned int*)g,
      (__attribute__((address_space(3))) unsigned int*)l, 16, 0, 0);
}

// ---------------- grid barrier (all NBLK blocks co-resident) ----------------
__device__ __forceinline__ void gbar(unsigned* cnt, unsigned* gen) {
  __syncthreads();
  if (threadIdx.x == 0) {
    unsigned g = __hip_atomic_load(gen, __ATOMIC_RELAXED, __HIP_MEMORY_SCOPE_AGENT);
    unsigned arrived = __hip_atomic_fetch_add(cnt, 1u, __ATOMIC_ACQ_REL,
                                              __HIP_MEMORY_SCOPE_AGENT);
    if (arrived == NBLK - 1) {
      __hip_atomic_store(cnt, 0u, __ATOMIC_RELAXED, __HIP_MEMORY_SCOPE_AGENT);
      __hip_atomic_fetch_add(gen, 1u, __ATOMIC_ACQ_REL, __HIP_MEMORY_SCOPE_AGENT);
    } else {
      while (__hip_atomic_load(gen, __ATOMIC_ACQUIRE,
                               __HIP_MEMORY_SCOPE_AGENT) == g)
        __builtin_amdgcn_s_sleep(2);
    }
  }
  __syncthreads();
}

// ---------------- conversion / prep kernels ----------------

__global__ __launch_bounds__(256) void split_bf16_kernel(
    const float* __restrict__ x, __hip_bfloat16* __restrict__ hi,
    __hip_bfloat16* __restrict__ lo, int n)
{
  int i = blockIdx.x * blockDim.x + threadIdx.x;
  int stride = gridDim.x * blockDim.x;
  for (; i < n; i += stride) {
    float v = x[i];
    __hip_bfloat16 h = __float2bfloat16(v);
    hi[i] = h;
    lo[i] = __float2bfloat16(v - __bfloat162float(h));
  }
}

// permute rows j' = 3u+g  <-  source row g*1024+u ; split to bf16 hi/lo.
// WcH/WcL are rows 0..3071 of the combined B matrix (rows 3072..4095 = Wa).
__global__ __launch_bounds__(256) void prep_weights(
    const float* __restrict__ Wih, const float* __restrict__ Whh,
    const float* __restrict__ bih, const float* __restrict__ bhh,
    __hip_bfloat16* __restrict__ WcH, __hip_bfloat16* __restrict__ WcL,
    __hip_bfloat16* __restrict__ We,
    __hip_bfloat16* __restrict__ WhH, __hip_bfloat16* __restrict__ WhL,
    float* __restrict__ bihp, float* __restrict__ bhhp)
{
  const int jp = blockIdx.x;           // 0..3071
  const int u = jp / 3, g = jp - 3 * u;
  const int src = g * 1024 + u;
  for (int c = threadIdx.x; c < 2048; c += 256) {
    float v = Wih[(size_t)src * 2560 + 512 + c];
    __hip_bfloat16 h = __float2bfloat16(v);
    WcH[(size_t)jp * 2048 + c] = h;
    WcL[(size_t)jp * 2048 + c] = __float2bfloat16(v - __bfloat162float(h));
  }
  for (int c = threadIdx.x; c < 512; c += 256)
    We[(size_t)jp * 512 + c] = __float2bfloat16(Wih[(size_t)src * 2560 + c]);
  for (int c = threadIdx.x; c < 1024; c += 256) {
    float v = Whh[(size_t)src * 1024 + c];
    __hip_bfloat16 h = __float2bfloat16(v);
    WhH[(size_t)jp * 1024 + c] = h;
    WhL[(size_t)jp * 1024 + c] = __float2bfloat16(v - __bfloat162float(h));
  }
  if (threadIdx.x == 0) { bihp[jp] = bih[src]; bhhp[jp] = bhh[src]; }
}

__global__ __launch_bounds__(256) void emb_gather(
    const int* __restrict__ tgt, const float* __restrict__ table,
    __hip_bfloat16* __restrict__ outb)
{
  const int row = blockIdx.x;          // b*64+t, 0..4095
  const int v = tgt[row];
  for (int c = threadIdx.x; c < 512; c += 256)
    outb[(size_t)row * 512 + c] = __float2bfloat16(table[(size_t)v * 512 + c]);
}

__global__ __launch_bounds__(256) void h0_init(
    const float* __restrict__ h0, float* __restrict__ hf,
    __hip_bfloat16* __restrict__ hhi, __hip_bfloat16* __restrict__ hlo,
    unsigned* __restrict__ bar)
{
  const int i = blockIdx.x * 256 + threadIdx.x;   // grid 256 -> 65536
  float v = h0[i];
  hf[i] = v;
  __hip_bfloat16 h = __float2bfloat16(v);
  hhi[i] = h;
  hlo[i] = __float2bfloat16(v - __bfloat162float(h));
  if (i < 8) bar[i] = 0u;   // zero barrier state (ws is poisoned each call)
}

// ---------------- bf16 GEMM  C[M,N] = A[M,K] @ B[N,K]^T (single pass) -------

__global__ __launch_bounds__(256) void gemm_bt(
    const short* __restrict__ A, const short* __restrict__ B,
    float* __restrict__ Cf, __hip_bfloat16* __restrict__ Cb,
    const float* __restrict__ bias, int M, int N, int K, int flags)
{
  __shared__ __align__(16) short As[128 * 32];
  __shared__ __align__(16) short Bs[128 * 32];
  const int tid = threadIdx.x, lane = tid & 63, w = tid >> 6;
  const int m0 = blockIdx.y * 128, n0 = blockIdx.x * 128;
  const int wm = (w >> 1) * 64, wn = (w & 1) * 64;
  const int srow = lane >> 2, scol = (lane & 3) * 8;
  f32x4 zero = {0.f, 0.f, 0.f, 0.f};
  f32x4 acc[4][4];
#pragma unroll
  for (int i = 0; i < 4; ++i)
#pragma unroll
    for (int j = 0; j < 4; ++j) acc[i][j] = zero;

  for (int k0 = 0; k0 < K; k0 += 32) {
    __syncthreads();
#pragma unroll
    for (int s = 0; s < 2; ++s) {
      const int chunk = w * 2 + s;
      const int r = chunk * 16 + srow;
      gld16(A + (size_t)(m0 + r) * K + k0 + scol, As + chunk * 512);
      gld16(B + (size_t)(n0 + r) * K + k0 + scol, Bs + chunk * 512);
    }
    __syncthreads();
    const int fm = lane & 15, fq = lane >> 4;
    short8 af[4], bq[4];
#pragma unroll
    for (int i = 0; i < 4; ++i)
      af[i] = *(const short8*)(As + (wm + i * 16 + fm) * 32 + fq * 8);
#pragma unroll
    for (int j = 0; j < 4; ++j)
      bq[j] = *(const short8*)(Bs + (wn + j * 16 + fm) * 32 + fq * 8);
#pragma unroll
    for (int i = 0; i < 4; ++i)
#pragma unroll
      for (int j = 0; j < 4; ++j)
        acc[i][j] = __builtin_amdgcn_mfma_f32_16x16x32_bf16(af[i], bq[j], acc[i][j], 0, 0, 0);
  }

  const int cn = lane & 15, cq = (lane >> 4) * 4;
#pragma unroll
  for (int i = 0; i < 4; ++i)
#pragma unroll
    for (int j = 0; j < 4; ++j)
#pragma unroll
      for (int r = 0; r < 4; ++r) {
        const int m = m0 + wm + i * 16 + cq + r;
        const int n = n0 + wn + j * 16 + cn;
        float v = acc[i][j][r];
        if (flags & FLAG_ACC) v += Cf[(size_t)m * N + n];
        if (bias) v += bias[n];
        if (flags & FLAG_BF) Cb[(size_t)m * N + n] = __float2bfloat16(v);
        else                 Cf[(size_t)m * N + n] = v;
      }
}

// ---------------- fused split-bf16 triple GEMM --------------------------------
// C = AH@BH^T + AL@BH^T + AH@BL^T  (effective-fp32 product), one staging pass.

__global__ __launch_bounds__(256) void gemm_bt3(
    const short* __restrict__ AH, const short* __restrict__ AL,
    const short* __restrict__ BH, const short* __restrict__ BL,
    float* __restrict__ Cf, int M, int N, int K)
{
  __shared__ __align__(16) short AsH[128 * 32];
  __shared__ __align__(16) short AsL[128 * 32];
  __shared__ __align__(16) short BsH[128 * 32];
  __shared__ __align__(16) short BsL[128 * 32];
  const int tid = threadIdx.x, lane = tid & 63, w = tid >> 6;
  const int m0 = blockIdx.y * 128, n0 = blockIdx.x * 128;
  const int wm = (w >> 1) * 64, wn = (w & 1) * 64;
  const int srow = lane >> 2, scol = (lane & 3) * 8;
  f32x4 zero = {0.f, 0.f, 0.f, 0.f};
  f32x4 acc[4][4];
#pragma unroll
  for (int i = 0; i < 4; ++i)
#pragma unroll
    for (int j = 0; j < 4; ++j) acc[i][j] = zero;

  for (int k0 = 0; k0 < K; k0 += 32) {
    __syncthreads();
#pragma unroll
    for (int s = 0; s < 2; ++s) {
      const int chunk = w * 2 + s;
      const int r = chunk * 16 + srow;
      const size_t ao = (size_t)(m0 + r) * K + k0 + scol;
      const size_t bo = (size_t)(n0 + r) * K + k0 + scol;
      gld16(AH + ao, AsH + chunk * 512);
      gld16(AL + ao, AsL + chunk * 512);
      gld16(BH + bo, BsH + chunk * 512);
      gld16(BL + bo, BsL + chunk * 512);
    }
    __syncthreads();
    const int fm = lane & 15, fq = lane >> 4;
    short8 ah[4], al[4], bh[4], bl[4];
#pragma unroll
    for (int i = 0; i < 4; ++i) {
      const int off = (wm + i * 16 + fm) * 32 + fq * 8;
      ah[i] = *(const short8*)(AsH + off);
      al[i] = *(const short8*)(AsL + off);
    }
#pragma unroll
    for (int j = 0; j < 4; ++j) {
      const int off = (wn + j * 16 + fm) * 32 + fq * 8;
      bh[j] = *(const short8*)(BsH + off);
      bl[j] = *(const short8*)(BsL + off);
    }
#pragma unroll
    for (int i = 0; i < 4; ++i)
#pragma unroll
      for (int j = 0; j < 4; ++j) {
        acc[i][j] = __builtin_amdgcn_mfma_f32_16x16x32_bf16(ah[i], bh[j], acc[i][j], 0, 0, 0);
        acc[i][j] = __builtin_amdgcn_mfma_f32_16x16x32_bf16(al[i], bh[j], acc[i][j], 0, 0, 0);
        acc[i][j] = __builtin_amdgcn_mfma_f32_16x16x32_bf16(ah[i], bl[j], acc[i][j], 0, 0, 0);
      }
  }

  const int cn = lane & 15, cq = (lane >> 4) * 4;
#pragma unroll
  for (int i = 0; i < 4; ++i)
#pragma unroll
    for (int j = 0; j < 4; ++j)
#pragma unroll
      for (int r = 0; r < 4; ++r) {
        const int m = m0 + wm + i * 16 + cq + r;
        const int n = n0 + wn + j * 16 + cn;
        Cf[(size_t)m * N + n] = acc[i][j][r];
      }
}

// ---------------- THE persistent loop kernel ----------------------------------
// 256 blocks x 256 threads, all co-resident (tiny LDS, <=1 block/CU needed).
// Per step t:
//   phase A: blocks 0..63   : attn for batch b (scores fp32 vs ctxW cols of Cc,
//                             masked softmax, write attnG)
//            blocks 64..159 : gh = Whh@h split-bf16 3-pass MFMA, 32 j'-rows each
//                             -> ghG fp32
//            blocks 160..255: idle
//   [grid barrier]
//   phase B: all 256 as (jc 0..63, bc 0..3): compacted-attention ctxWc
//            contraction + gates + h update (hf, hhi, hlo, out)
//   [grid barrier]

__global__ __launch_bounds__(256, 1) void rnn_loop(
    const float* __restrict__ Cc,      // [4096][4096]: cols 0..3071 ctxWc, 3072+ ctxW
    const int* __restrict__ lens,
    const short* __restrict__ WhH, const short* __restrict__ WhL,
    const __hip_bfloat16* __restrict__ gxe, const float* __restrict__ bhhp,
    float* __restrict__ hf, short* __restrict__ hhi, short* __restrict__ hlo,
    float* __restrict__ attnG, float* __restrict__ ghG,
    float* __restrict__ out, unsigned* __restrict__ bar)
{
  __shared__ union {
    struct { float hs[1024]; float part[256]; } a;
    struct { float ghs[48 * 17]; float wv[16][64]; short lidx[16][64]; int cnt[16]; } b;
  } sm;

  const int blk = blockIdx.x, tid = threadIdx.x;
  const int lane = tid & 63, w = tid >> 6;
  const int fm = lane & 15, fq = lane >> 4;
  const f32x4 zero = {0.f, 0.f, 0.f, 0.f};

  for (int t = 0; t < 64; ++t) {
    // ---------------- phase A ----------------
    if (blk < 64) {
      // attention for batch b
      const int b = blk;
      const int len = lens[b];
      ((float4*)sm.a.hs)[tid] = ((const float4*)(hf + b * 1024))[tid];
      __syncthreads();
      const int l = tid >> 2, q = tid & 3;
      float s = 0.f;
      if (l < len) {
        const float4* row =
            (const float4*)(Cc + (size_t)(b * 64 + l) * 4096 + 3072 + q * 256);
        const float4* hh = (const float4*)(sm.a.hs + q * 256);
#pragma unroll 8
        for (int i = 0; i < 64; ++i) {
          float4 a = row[i], c = hh[i];
          s += a.x * c.x + a.y * c.y + a.z * c.z + a.w * c.w;
        }
      }
      sm.a.part[tid] = s;
      __syncthreads();
      if (tid < 64) {   // wave 0; tid == context position
        float sc = sm.a.part[tid * 4] + sm.a.part[tid * 4 + 1] +
                   sm.a.part[tid * 4 + 2] + sm.a.part[tid * 4 + 3];
        if (tid >= len) sc = -1e9f;
        float m = sc;
#pragma unroll
        for (int off = 32; off > 0; off >>= 1) m = fmaxf(m, __shfl_xor(m, off));
        float e = __expf(sc - m);
        float sum = e;
#pragma unroll
        for (int off = 32; off > 0; off >>= 1) sum += __shfl_xor(sum, off);
        attnG[b * 64 + tid] = e / sum;
      }
    } else if (blk < 160) {
      // gh = Whh_slice @ h, split-bf16 3-pass MFMA; 32 j'-rows per block
      const int j0 = (blk - 64) * 32;
      f32x4 acc0 = zero, acc1 = zero;
      const short* ah  = hhi + (w * 16 + fm) * 1024 + fq * 8;   // batches w*16..+15
      const short* al  = hlo + (w * 16 + fm) * 1024 + fq * 8;
      const short* bh0 = WhH + (size_t)(j0 + fm) * 1024 + fq * 8;
      const short* bh1 = WhH + (size_t)(j0 + 16 + fm) * 1024 + fq * 8;
      const short* bl0 = WhL + (size_t)(j0 + fm) * 1024 + fq * 8;
      const short* bl1 = WhL + (size_t)(j0 + 16 + fm) * 1024 + fq * 8;
#pragma unroll 2
      for (int k0 = 0; k0 < 1024; k0 += 32) {
        short8 aH = *(const short8*)(ah + k0);
        short8 aL = *(const short8*)(al + k0);
        short8 b0 = *(const short8*)(bh0 + k0);
        short8 b1 = *(const short8*)(bh1 + k0);
        short8 c0 = *(const short8*)(bl0 + k0);
        short8 c1 = *(const short8*)(bl1 + k0);
        acc0 = __builtin_amdgcn_mfma_f32_16x16x32_bf16(aH, b0, acc0, 0, 0, 0);
        acc1 = __builtin_amdgcn_mfma_f32_16x16x32_bf16(aH, b1, acc1, 0, 0, 0);
        acc0 = __builtin_amdgcn_mfma_f32_16x16x32_bf16(aL, b0, acc0, 0, 0, 0);
        acc1 = __builtin_amdgcn_mfma_f32_16x16x32_bf16(aL, b1, acc1, 0, 0, 0);
        acc0 = __builtin_amdgcn_mfma_f32_16x16x32_bf16(aH, c0, acc0, 0, 0, 0);
        acc1 = __builtin_amdgcn_mfma_f32_16x16x32_bf16(aH, c1, acc1, 0, 0, 0);
      }
      const int mb = w * 16 + fq * 4;
      *(f32x4*)(ghG + (size_t)(j0 + fm) * 64 + mb) = acc0;
      *(f32x4*)(ghG + (size_t)(j0 + 16 + fm) * 64 + mb) = acc1;
    }
    gbar(bar, bar + 1);

    // ---------------- phase B: gates ----------------
    {
      const int jc = blk & 63, bc = blk >> 6;
      const int j0b = jc * 48, b0 = bc * 16;
      if (tid < 16) sm.b.cnt[tid] = 0;
      for (int i = tid; i < 768; i += 256) {
        const int row = i >> 4, col = i & 15;
        sm.b.ghs[row * 17 + col] = ghG[(size_t)(j0b + row) * 64 + b0 + col];
      }
      __syncthreads();
      {
        const int bb = tid >> 4, l4 = (tid & 15) * 4;
        const int b = b0 + bb, len = lens[b];
#pragma unroll
        for (int k = 0; k < 4; ++k) {
          const int l = l4 + k;
          const float wl = attnG[b * 64 + l];
          if (l < len && wl >= 1e-8f) {
            const int pos = atomicAdd(&sm.b.cnt[bb], 1);
            sm.b.lidx[bb][pos] = (short)l;
            sm.b.wv[bb][pos] = wl;
          }
        }
      }
      __syncthreads();

      const int bb = tid >> 4, jg = tid & 15;
      const int b = b0 + bb;
      const int n = sm.b.cnt[bb];
      float g0 = 0.f, g1 = 0.f, g2 = 0.f;
      const float* base = Cc + (size_t)(b * 64) * 4096 + j0b + jg * 3;
      int i = 0;
      for (; i + 1 < n; i += 2) {
        const float wa = sm.b.wv[bb][i], wb2 = sm.b.wv[bb][i + 1];
        const float* pa = base + (size_t)sm.b.lidx[bb][i] * 4096;
        const float* pb = base + (size_t)sm.b.lidx[bb][i + 1] * 4096;
        g0 += wa * pa[0] + wb2 * pb[0];
        g1 += wa * pa[1] + wb2 * pb[1];
        g2 += wa * pa[2] + wb2 * pb[2];
      }
      if (i < n) {
        const float wa = sm.b.wv[bb][i];
        const float* pa = base + (size_t)sm.b.lidx[bb][i] * 4096;
        g0 += wa * pa[0]; g1 += wa * pa[1]; g2 += wa * pa[2];
      }

      const int jp = j0b + jg * 3;
      const __hip_bfloat16* ge = gxe + (size_t)(b * 64 + t) * 3072 + jp;
      const float gxr = g0 + __bfloat162float(ge[0]);
      const float gxz = g1 + __bfloat162float(ge[1]);
      const float gxn = g2 + __bfloat162float(ge[2]);
      const float ghr = sm.b.ghs[(jg * 3 + 0) * 17 + bb] + bhhp[jp + 0];
      const float ghz = sm.b.ghs[(jg * 3 + 1) * 17 + bb] + bhhp[jp + 1];
      const float ghn = sm.b.ghs[(jg * 3 + 2) * 17 + bb] + bhhp[jp + 2];
      const float rr = 1.f / (1.f + __expf(-(gxr + ghr)));
      const float zz = 1.f / (1.f + __expf(-(gxz + ghz)));
      const float nn = tanhf(gxn + rr * ghn);
      const int u = jc * 16 + jg;
      const float hold = hf[b * 1024 + u];
      const float hn = (1.f - zz) * nn + zz * hold;
      out[(size_t)(b * 64 + t) * 1024 + u] = hn;
      hf[b * 1024 + u] = hn;
      __hip_bfloat16 hh = __float2bfloat16(hn);
      hhi[b * 1024 + u] = *reinterpret_cast<short*>(&hh);
      __hip_bfloat16 hl = __float2bfloat16(hn - __bfloat162float(hh));
      hlo[b * 1024 + u] = *reinterpret_cast<short*>(&hl);
      if (t == 63) out[(size_t)64 * 64 * 1024 + b * 1024 + u] = hn;
    }
    gbar(bar, bar + 1);
  }
}

// ---------------- launcher ----------------

extern "C" void kernel_launch(void* const* d_in, const int* in_sizes, int n_in,
                              void* d_out, int out_size, void* d_ws, size_t ws_size,
                              hipStream_t stream)
{
  const int*   tgt  = (const int*)  d_in[0];
  const float* ctx  = (const float*)d_in[1];
  const float* h0   = (const float*)d_in[2];
  const int*   lens = (const int*)  d_in[3];
  const float* embt = (const float*)d_in[4];
  const float* Wa   = (const float*)d_in[5];
  const float* Wih  = (const float*)d_in[6];
  const float* Whh  = (const float*)d_in[7];
  const float* bih  = (const float*)d_in[8];
  const float* bhh  = (const float*)d_in[9];
  float* out = (float*)d_out;

  char* p = (char*)d_ws;
  auto take = [&](size_t bytes) {
    char* q = p;
    p += (bytes + 255) & ~(size_t)255;
    return q;
  };
  short* ctx_hi = (short*)take((size_t)8388608 * 2);
  short* ctx_lo = (short*)take((size_t)8388608 * 2);
  short* BcH    = (short*)take((size_t)4096 * 2048 * 2);  // rows 0..3071 Wc, 3072+ Wa
  short* BcL    = (short*)take((size_t)4096 * 2048 * 2);
  short* We_p   = (short*)take((size_t)3072 * 512 * 2);
  short* WhH    = (short*)take((size_t)3072 * 1024 * 2);
  short* WhL    = (short*)take((size_t)3072 * 1024 * 2);
  float* bih_p  = (float*)take(3072 * 4);
  float* bhh_p  = (float*)take(3072 * 4);
  short* emb_bf = (short*)take((size_t)4096 * 512 * 2);
  float* Cc     = (float*)take((size_t)4096 * 4096 * 4);  // ctxWc | ctxW
  short* gxe    = (short*)take((size_t)4096 * 3072 * 2);
  float* hf     = (float*)take((size_t)65536 * 4);
  short* hhi    = (short*)take((size_t)65536 * 2);
  short* hlo    = (short*)take((size_t)65536 * 2);
  float* attn   = (float*)take((size_t)4096 * 4);
  float* ghG    = (float*)take((size_t)3072 * 64 * 4);
  unsigned* bar = (unsigned*)take(8 * 4);

  // prologue: conversions
  split_bf16_kernel<<<2048, 256, 0, stream>>>(ctx, (__hip_bfloat16*)ctx_hi,
                                              (__hip_bfloat16*)ctx_lo, 8388608);
  split_bf16_kernel<<<1024, 256, 0, stream>>>(Wa,
      (__hip_bfloat16*)(BcH + (size_t)3072 * 2048),
      (__hip_bfloat16*)(BcL + (size_t)3072 * 2048), 2097152);
  prep_weights<<<3072, 256, 0, stream>>>(Wih, Whh, bih, bhh,
      (__hip_bfloat16*)BcH, (__hip_bfloat16*)BcL, (__hip_bfloat16*)We_p,
      (__hip_bfloat16*)WhH, (__hip_bfloat16*)WhL, bih_p, bhh_p);
  emb_gather<<<4096, 256, 0, stream>>>(tgt, embt, (__hip_bfloat16*)emb_bf);
  h0_init<<<256, 256, 0, stream>>>(h0, hf, (__hip_bfloat16*)hhi,
                                   (__hip_bfloat16*)hlo, bar);

  // Cc = ctx @ [Wc_perm; Wa]^T  (split-bf16 fused 3-product, fp32 out)
  gemm_bt3<<<dim3(32, 32), 256, 0, stream>>>(ctx_hi, ctx_lo, BcH, BcL,
                                             Cc, 4096, 4096, 2048);
  // gxe = emb @ We_perm^T + b_ih (bf16 out; |gxe| ~ 3e-3, rounding negligible)
  gemm_bt<<<dim3(24, 32), 256, 0, stream>>>(emb_bf, We_p, nullptr,
                                            (__hip_bfloat16*)gxe, bih_p,
                                            4096, 3072, 512, FLAG_BF);

  // the whole 64-step recurrence in one persistent kernel
  rnn_loop<<<NBLK, 256, 0, stream>>>(Cc, lens, WhH, WhL,
      (const __hip_bfloat16*)gxe, bhh_p, hf, hhi, hlo, attn, ghG, out, bar);
}

// Round 5
// 5593.629 us; speedup vs baseline: 1.3772x; 1.3772x over previous
//
#include <hip/hip_runtime.h>
#include <hip/hip_bf16.h>

// DecoderRNNsearch on MI355X — round 5: persistent loop with RELAXED-atomic
// barrier + per-access coherent data ops (no cache-wide invalidation).
// Round-4 failure: ACQUIRE/ACQ_REL agent atomics emit buffer_inv/wb per
// barrier/spin -> 57us/barrier and L2 residency destroyed (FETCH 1.6GB).
// Now: cross-block data (hf, hpk, attnG, ghG) uses RELAXED AGENT atomic
// load/store (per-access coherence); barrier is a monotonic relaxed counter;
// __syncthreads() (which drains vmcnt per wave) orders stores before arrival.
// Read-only data (Whh planes, Cc, gxe) keeps normal cached loads -> L2-hot.

using short8 = __attribute__((ext_vector_type(8))) short;
using f32x4  = __attribute__((ext_vector_type(4))) float;

#define FLAG_ACC 1
#define FLAG_BF  2
#define NBLK 256

__device__ __forceinline__ void gld16(const void* g, void* l) {
  __builtin_amdgcn_global_load_lds(
      (const __attribute__((address_space(1))) unsigned int*)g,
      (__attribute__((address_space(3))) unsigned int*)l, 16, 0, 0);
}

// ---- per-access coherent (agent-scope, relaxed) load/store helpers ----
__device__ __forceinline__ float cloadf(const float* p) {
  return __hip_atomic_load((float*)p, __ATOMIC_RELAXED, __HIP_MEMORY_SCOPE_AGENT);
}
__device__ __forceinline__ void cstoref(float* p, float v) {
  __hip_atomic_store(p, v, __ATOMIC_RELAXED, __HIP_MEMORY_SCOPE_AGENT);
}
__device__ __forceinline__ unsigned long long cload64(const void* p) {
  return __hip_atomic_load((unsigned long long*)p, __ATOMIC_RELAXED,
                           __HIP_MEMORY_SCOPE_AGENT);
}
__device__ __forceinline__ void cstore64(void* p, unsigned long long v) {
  __hip_atomic_store((unsigned long long*)p, v, __ATOMIC_RELAXED,
                     __HIP_MEMORY_SCOPE_AGENT);
}
__device__ __forceinline__ void cstoreu(unsigned int* p, unsigned int v) {
  __hip_atomic_store(p, v, __ATOMIC_RELAXED, __HIP_MEMORY_SCOPE_AGENT);
}

// ---- grid barrier: monotonic counter, all-relaxed (no cache maintenance) ----
// __syncthreads() before arrival drains each wave's vmcnt -> all coherent
// stores of this block are at the coherence point before the counter bumps.
__device__ __forceinline__ void gbar(unsigned* cnt, unsigned target) {
  __syncthreads();
  if (threadIdx.x == 0) {
    __hip_atomic_fetch_add(cnt, 1u, __ATOMIC_RELAXED, __HIP_MEMORY_SCOPE_AGENT);
    while (__hip_atomic_load(cnt, __ATOMIC_RELAXED,
                             __HIP_MEMORY_SCOPE_AGENT) < target)
      __builtin_amdgcn_s_sleep(1);
  }
  __syncthreads();
}

// ---------------- conversion / prep kernels ----------------

__global__ __launch_bounds__(256) void split_bf16_kernel(
    const float* __restrict__ x, __hip_bfloat16* __restrict__ hi,
    __hip_bfloat16* __restrict__ lo, int n)
{
  int i = blockIdx.x * blockDim.x + threadIdx.x;
  int stride = gridDim.x * blockDim.x;
  for (; i < n; i += stride) {
    float v = x[i];
    __hip_bfloat16 h = __float2bfloat16(v);
    hi[i] = h;
    lo[i] = __float2bfloat16(v - __bfloat162float(h));
  }
}

// permute rows j' = 3u+g  <-  source row g*1024+u ; split to bf16 hi/lo.
__global__ __launch_bounds__(256) void prep_weights(
    const float* __restrict__ Wih, const float* __restrict__ Whh,
    const float* __restrict__ bih, const float* __restrict__ bhh,
    __hip_bfloat16* __restrict__ WcH, __hip_bfloat16* __restrict__ WcL,
    __hip_bfloat16* __restrict__ We,
    __hip_bfloat16* __restrict__ WhH, __hip_bfloat16* __restrict__ WhL,
    float* __restrict__ bihp, float* __restrict__ bhhp)
{
  const int jp = blockIdx.x;           // 0..3071
  const int u = jp / 3, g = jp - 3 * u;
  const int src = g * 1024 + u;
  for (int c = threadIdx.x; c < 2048; c += 256) {
    float v = Wih[(size_t)src * 2560 + 512 + c];
    __hip_bfloat16 h = __float2bfloat16(v);
    WcH[(size_t)jp * 2048 + c] = h;
    WcL[(size_t)jp * 2048 + c] = __float2bfloat16(v - __bfloat162float(h));
  }
  for (int c = threadIdx.x; c < 512; c += 256)
    We[(size_t)jp * 512 + c] = __float2bfloat16(Wih[(size_t)src * 2560 + c]);
  for (int c = threadIdx.x; c < 1024; c += 256) {
    float v = Whh[(size_t)src * 1024 + c];
    __hip_bfloat16 h = __float2bfloat16(v);
    WhH[(size_t)jp * 1024 + c] = h;
    WhL[(size_t)jp * 1024 + c] = __float2bfloat16(v - __bfloat162float(h));
  }
  if (threadIdx.x == 0) { bihp[jp] = bih[src]; bhhp[jp] = bhh[src]; }
}

__global__ __launch_bounds__(256) void emb_gather(
    const int* __restrict__ tgt, const float* __restrict__ table,
    __hip_bfloat16* __restrict__ outb)
{
  const int row = blockIdx.x;          // b*64+t, 0..4095
  const int v = tgt[row];
  for (int c = threadIdx.x; c < 512; c += 256)
    outb[(size_t)row * 512 + c] = __float2bfloat16(table[(size_t)v * 512 + c]);
}

__global__ __launch_bounds__(256) void h0_init(
    const float* __restrict__ h0, float* __restrict__ hf,
    unsigned int* __restrict__ hpk, unsigned* __restrict__ bar)
{
  const int i = blockIdx.x * 256 + threadIdx.x;   // grid 256 -> 65536
  float v = h0[i];
  hf[i] = v;
  __hip_bfloat16 h = __float2bfloat16(v);
  __hip_bfloat16 l = __float2bfloat16(v - __bfloat162float(h));
  hpk[i] = (unsigned)*(unsigned short*)&h | ((unsigned)*(unsigned short*)&l << 16);
  if (i < 8) bar[i] = 0u;
}

// ---------------- bf16 GEMM  C[M,N] = A[M,K] @ B[N,K]^T (single pass) -------

__global__ __launch_bounds__(256) void gemm_bt(
    const short* __restrict__ A, const short* __restrict__ B,
    float* __restrict__ Cf, __hip_bfloat16* __restrict__ Cb,
    const float* __restrict__ bias, int M, int N, int K, int flags)
{
  __shared__ __align__(16) short As[128 * 32];
  __shared__ __align__(16) short Bs[128 * 32];
  const int tid = threadIdx.x, lane = tid & 63, w = tid >> 6;
  const int m0 = blockIdx.y * 128, n0 = blockIdx.x * 128;
  const int wm = (w >> 1) * 64, wn = (w & 1) * 64;
  const int srow = lane >> 2, scol = (lane & 3) * 8;
  f32x4 zero = {0.f, 0.f, 0.f, 0.f};
  f32x4 acc[4][4];
#pragma unroll
  for (int i = 0; i < 4; ++i)
#pragma unroll
    for (int j = 0; j < 4; ++j) acc[i][j] = zero;

  for (int k0 = 0; k0 < K; k0 += 32) {
    __syncthreads();
#pragma unroll
    for (int s = 0; s < 2; ++s) {
      const int chunk = w * 2 + s;
      const int r = chunk * 16 + srow;
      gld16(A + (size_t)(m0 + r) * K + k0 + scol, As + chunk * 512);
      gld16(B + (size_t)(n0 + r) * K + k0 + scol, Bs + chunk * 512);
    }
    __syncthreads();
    const int fm = lane & 15, fq = lane >> 4;
    short8 af[4], bq[4];
#pragma unroll
    for (int i = 0; i < 4; ++i)
      af[i] = *(const short8*)(As + (wm + i * 16 + fm) * 32 + fq * 8);
#pragma unroll
    for (int j = 0; j < 4; ++j)
      bq[j] = *(const short8*)(Bs + (wn + j * 16 + fm) * 32 + fq * 8);
#pragma unroll
    for (int i = 0; i < 4; ++i)
#pragma unroll
      for (int j = 0; j < 4; ++j)
        acc[i][j] = __builtin_amdgcn_mfma_f32_16x16x32_bf16(af[i], bq[j], acc[i][j], 0, 0, 0);
  }

  const int cn = lane & 15, cq = (lane >> 4) * 4;
#pragma unroll
  for (int i = 0; i < 4; ++i)
#pragma unroll
    for (int j = 0; j < 4; ++j)
#pragma unroll
      for (int r = 0; r < 4; ++r) {
        const int m = m0 + wm + i * 16 + cq + r;
        const int n = n0 + wn + j * 16 + cn;
        float v = acc[i][j][r];
        if (flags & FLAG_ACC) v += Cf[(size_t)m * N + n];
        if (bias) v += bias[n];
        if (flags & FLAG_BF) Cb[(size_t)m * N + n] = __float2bfloat16(v);
        else                 Cf[(size_t)m * N + n] = v;
      }
}

// ---------------- fused split-bf16 triple GEMM --------------------------------

__global__ __launch_bounds__(256) void gemm_bt3(
    const short* __restrict__ AH, const short* __restrict__ AL,
    const short* __restrict__ BH, const short* __restrict__ BL,
    float* __restrict__ Cf, int M, int N, int K)
{
  __shared__ __align__(16) short AsH[128 * 32];
  __shared__ __align__(16) short AsL[128 * 32];
  __shared__ __align__(16) short BsH[128 * 32];
  __shared__ __align__(16) short BsL[128 * 32];
  const int tid = threadIdx.x, lane = tid & 63, w = tid >> 6;
  const int m0 = blockIdx.y * 128, n0 = blockIdx.x * 128;
  const int wm = (w >> 1) * 64, wn = (w & 1) * 64;
  const int srow = lane >> 2, scol = (lane & 3) * 8;
  f32x4 zero = {0.f, 0.f, 0.f, 0.f};
  f32x4 acc[4][4];
#pragma unroll
  for (int i = 0; i < 4; ++i)
#pragma unroll
    for (int j = 0; j < 4; ++j) acc[i][j] = zero;

  for (int k0 = 0; k0 < K; k0 += 32) {
    __syncthreads();
#pragma unroll
    for (int s = 0; s < 2; ++s) {
      const int chunk = w * 2 + s;
      const int r = chunk * 16 + srow;
      const size_t ao = (size_t)(m0 + r) * K + k0 + scol;
      const size_t bo = (size_t)(n0 + r) * K + k0 + scol;
      gld16(AH + ao, AsH + chunk * 512);
      gld16(AL + ao, AsL + chunk * 512);
      gld16(BH + bo, BsH + chunk * 512);
      gld16(BL + bo, BsL + chunk * 512);
    }
    __syncthreads();
    const int fm = lane & 15, fq = lane >> 4;
    short8 ah[4], al[4], bh[4], bl[4];
#pragma unroll
    for (int i = 0; i < 4; ++i) {
      const int off = (wm + i * 16 + fm) * 32 + fq * 8;
      ah[i] = *(const short8*)(AsH + off);
      al[i] = *(const short8*)(AsL + off);
    }
#pragma unroll
    for (int j = 0; j < 4; ++j) {
      const int off = (wn + j * 16 + fm) * 32 + fq * 8;
      bh[j] = *(const short8*)(BsH + off);
      bl[j] = *(const short8*)(BsL + off);
    }
#pragma unroll
    for (int i = 0; i < 4; ++i)
#pragma unroll
      for (int j = 0; j < 4; ++j) {
        acc[i][j] = __builtin_amdgcn_mfma_f32_16x16x32_bf16(ah[i], bh[j], acc[i][j], 0, 0, 0);
        acc[i][j] = __builtin_amdgcn_mfma_f32_16x16x32_bf16(al[i], bh[j], acc[i][j], 0, 0, 0);
        acc[i][j] = __builtin_amdgcn_mfma_f32_16x16x32_bf16(ah[i], bl[j], acc[i][j], 0, 0, 0);
      }
  }

  const int cn = lane & 15, cq = (lane >> 4) * 4;
#pragma unroll
  for (int i = 0; i < 4; ++i)
#pragma unroll
    for (int j = 0; j < 4; ++j)
#pragma unroll
      for (int r = 0; r < 4; ++r) {
        const int m = m0 + wm + i * 16 + cq + r;
        const int n = n0 + wn + j * 16 + cn;
        Cf[(size_t)m * N + n] = acc[i][j][r];
      }
}

// ---------------- THE persistent loop kernel ----------------------------------
// 256 blocks x 256 threads. Per step:
//   phase A: blocks 0..63  : attn for batch b (coherent hf read, normal ctxW)
//            blocks 64..95 : gh = Whh@h split-bf16 3-pass MFMA, 96 j'-rows each
//                            (coherent packed-h reads, normal Whh reads)
//   [gbar]
//   phase B: 256 blocks (jc,bc): compacted-attn Cc contraction + gates,
//            coherent h/hpk stores.
//   [gbar]

__global__ __launch_bounds__(256, 1) void rnn_loop(
    const float* __restrict__ Cc,      // [4096][4096]: cols 0..3071 ctxWc, 3072+ ctxW
    const int* __restrict__ lens,
    const short* __restrict__ WhH, const short* __restrict__ WhL,
    const __hip_bfloat16* __restrict__ gxe, const float* __restrict__ bhhp,
    float* __restrict__ hf, unsigned int* __restrict__ hpk,
    float* __restrict__ attnG, float* __restrict__ ghG,
    float* __restrict__ out, unsigned* __restrict__ bar)
{
  __shared__ union {
    struct { float hs[1024]; float part[256]; } a;
    struct { float ghs[48 * 17]; float wv[16][64]; short lidx[16][64]; int cnt[16]; } b;
  } sm;

  const int blk = blockIdx.x, tid = threadIdx.x;
  const int lane = tid & 63, w = tid >> 6;
  const int fm = lane & 15, fq = lane >> 4;
  const f32x4 zero = {0.f, 0.f, 0.f, 0.f};
  unsigned bt = 0;

  for (int t = 0; t < 64; ++t) {
    // ---------------- phase A ----------------
    if (blk < 64) {
      const int b = blk;
      const int len = lens[b];
      {
        const unsigned long long* hp = (const unsigned long long*)(hf + b * 1024);
        unsigned long long v0 = cload64(hp + tid * 2);
        unsigned long long v1 = cload64(hp + tid * 2 + 1);
        float2 f0, f1;
        __builtin_memcpy(&f0, &v0, 8);
        __builtin_memcpy(&f1, &v1, 8);
        ((float2*)sm.a.hs)[tid * 2] = f0;
        ((float2*)sm.a.hs)[tid * 2 + 1] = f1;
      }
      __syncthreads();
      const int l = tid >> 2, q = tid & 3;
      float s = 0.f;
      if (l < len) {
        const float4* row =
            (const float4*)(Cc + (size_t)(b * 64 + l) * 4096 + 3072 + q * 256);
        const float4* hh = (const float4*)(sm.a.hs + q * 256);
#pragma unroll 8
        for (int i = 0; i < 64; ++i) {
          float4 a = row[i], c = hh[i];
          s += a.x * c.x + a.y * c.y + a.z * c.z + a.w * c.w;
        }
      }
      sm.a.part[tid] = s;
      __syncthreads();
      if (tid < 64) {   // wave 0; tid == context position
        float sc = sm.a.part[tid * 4] + sm.a.part[tid * 4 + 1] +
                   sm.a.part[tid * 4 + 2] + sm.a.part[tid * 4 + 3];
        if (tid >= len) sc = -1e9f;
        float m = sc;
#pragma unroll
        for (int off = 32; off > 0; off >>= 1) m = fmaxf(m, __shfl_xor(m, off));
        float e = __expf(sc - m);
        float sum = e;
#pragma unroll
        for (int off = 32; off > 0; off >>= 1) sum += __shfl_xor(sum, off);
        cstoref(&attnG[b * 64 + tid], e / sum);
      }
    } else if (blk < 96) {
      // gh: 96 j'-rows per block, split-bf16 3-pass; packed-h coherent reads
      const int j0 = (blk - 64) * 96;
      f32x4 acc[6];
#pragma unroll
      for (int g = 0; g < 6; ++g) acc[g] = zero;
      const unsigned int* hrow = hpk + (w * 16 + fm) * 1024 + fq * 8;
#pragma unroll 2
      for (int k0 = 0; k0 < 1024; k0 += 32) {
        union { unsigned long long q[4]; unsigned int u[8]; } A_;
        const unsigned long long* hq = (const unsigned long long*)(hrow + k0);
        A_.q[0] = cload64(hq + 0);
        A_.q[1] = cload64(hq + 1);
        A_.q[2] = cload64(hq + 2);
        A_.q[3] = cload64(hq + 3);
        union { unsigned int u[4]; short8 s; } H_, L_;
        H_.u[0] = __builtin_amdgcn_perm(A_.u[1], A_.u[0], 0x05040100u);
        H_.u[1] = __builtin_amdgcn_perm(A_.u[3], A_.u[2], 0x05040100u);
        H_.u[2] = __builtin_amdgcn_perm(A_.u[5], A_.u[4], 0x05040100u);
        H_.u[3] = __builtin_amdgcn_perm(A_.u[7], A_.u[6], 0x05040100u);
        L_.u[0] = __builtin_amdgcn_perm(A_.u[1], A_.u[0], 0x07060302u);
        L_.u[1] = __builtin_amdgcn_perm(A_.u[3], A_.u[2], 0x07060302u);
        L_.u[2] = __builtin_amdgcn_perm(A_.u[5], A_.u[4], 0x07060302u);
        L_.u[3] = __builtin_amdgcn_perm(A_.u[7], A_.u[6], 0x07060302u);
        const short8 aH = H_.s, aL = L_.s;
#pragma unroll
        for (int g = 0; g < 6; ++g) {
          const size_t boff = (size_t)(j0 + g * 16 + fm) * 1024 + fq * 8 + k0;
          short8 bh = *(const short8*)(WhH + boff);
          short8 bl = *(const short8*)(WhL + boff);
          acc[g] = __builtin_amdgcn_mfma_f32_16x16x32_bf16(aH, bh, acc[g], 0, 0, 0);
          acc[g] = __builtin_amdgcn_mfma_f32_16x16x32_bf16(aL, bh, acc[g], 0, 0, 0);
          acc[g] = __builtin_amdgcn_mfma_f32_16x16x32_bf16(aH, bl, acc[g], 0, 0, 0);
        }
      }
      const int mb = w * 16 + fq * 4;
#pragma unroll
      for (int g = 0; g < 6; ++g) {
        union { f32x4 v; unsigned long long q[2]; } P;
        P.v = acc[g];
        unsigned long long* dst =
            (unsigned long long*)(ghG + (size_t)(j0 + g * 16 + fm) * 64 + mb);
        cstore64(dst, P.q[0]);
        cstore64(dst + 1, P.q[1]);
      }
    }
    bt += NBLK;
    gbar(bar, bt);

    // ---------------- phase B: gates ----------------
    {
      const int jc = blk & 63, bc = blk >> 6;
      const int j0b = jc * 48, b0 = bc * 16;
      if (tid < 16) sm.b.cnt[tid] = 0;
      for (int i = tid; i < 768; i += 256) {
        const int row = i >> 4, col = i & 15;
        sm.b.ghs[row * 17 + col] = cloadf(&ghG[(size_t)(j0b + row) * 64 + b0 + col]);
      }
      __syncthreads();
      {
        const int bb = tid >> 4, l4 = (tid & 15) * 4;
        const int b = b0 + bb, len = lens[b];
#pragma unroll
        for (int k = 0; k < 4; ++k) {
          const int l = l4 + k;
          const float wl = cloadf(&attnG[b * 64 + l]);
          if (l < len && wl >= 1e-8f) {
            const int pos = atomicAdd(&sm.b.cnt[bb], 1);
            sm.b.lidx[bb][pos] = (short)l;
            sm.b.wv[bb][pos] = wl;
          }
        }
      }
      __syncthreads();

      const int bb = tid >> 4, jg = tid & 15;
      const int b = b0 + bb;
      const int n = sm.b.cnt[bb];
      float g0 = 0.f, g1 = 0.f, g2 = 0.f;
      const float* base = Cc + (size_t)(b * 64) * 4096 + j0b + jg * 3;
      int i = 0;
      for (; i + 1 < n; i += 2) {
        const float wa = sm.b.wv[bb][i], wb2 = sm.b.wv[bb][i + 1];
        const float* pa = base + (size_t)sm.b.lidx[bb][i] * 4096;
        const float* pb = base + (size_t)sm.b.lidx[bb][i + 1] * 4096;
        g0 += wa * pa[0] + wb2 * pb[0];
        g1 += wa * pa[1] + wb2 * pb[1];
        g2 += wa * pa[2] + wb2 * pb[2];
      }
      if (i < n) {
        const float wa = sm.b.wv[bb][i];
        const float* pa = base + (size_t)sm.b.lidx[bb][i] * 4096;
        g0 += wa * pa[0]; g1 += wa * pa[1]; g2 += wa * pa[2];
      }

      const int jp = j0b + jg * 3;
      const __hip_bfloat16* ge = gxe + (size_t)(b * 64 + t) * 3072 + jp;
      const float gxr = g0 + __bfloat162float(ge[0]);
      const float gxz = g1 + __bfloat162float(ge[1]);
      const float gxn = g2 + __bfloat162float(ge[2]);
      const float ghr = sm.b.ghs[(jg * 3 + 0) * 17 + bb] + bhhp[jp + 0];
      const float ghz = sm.b.ghs[(jg * 3 + 1) * 17 + bb] + bhhp[jp + 1];
      const float ghn = sm.b.ghs[(jg * 3 + 2) * 17 + bb] + bhhp[jp + 2];
      const float rr = 1.f / (1.f + __expf(-(gxr + ghr)));
      const float zz = 1.f / (1.f + __expf(-(gxz + ghz)));
      const float nn = tanhf(gxn + rr * ghn);
      const int u = jc * 16 + jg;
      const float hold = cloadf(&hf[b * 1024 + u]);
      const float hn = (1.f - zz) * nn + zz * hold;
      out[(size_t)(b * 64 + t) * 1024 + u] = hn;
      cstoref(&hf[b * 1024 + u], hn);
      __hip_bfloat16 hh = __float2bfloat16(hn);
      __hip_bfloat16 hl = __float2bfloat16(hn - __bfloat162float(hh));
      unsigned int pk = (unsigned)*(unsigned short*)&hh |
                        ((unsigned)*(unsigned short*)&hl << 16);
      cstoreu(&hpk[b * 1024 + u], pk);
      if (t == 63) out[(size_t)64 * 64 * 1024 + b * 1024 + u] = hn;
    }
    bt += NBLK;
    gbar(bar, bt);
  }
}

// ---------------- launcher ----------------

extern "C" void kernel_launch(void* const* d_in, const int* in_sizes, int n_in,
                              void* d_out, int out_size, void* d_ws, size_t ws_size,
                              hipStream_t stream)
{
  const int*   tgt  = (const int*)  d_in[0];
  const float* ctx  = (const float*)d_in[1];
  const float* h0   = (const float*)d_in[2];
  const int*   lens = (const int*)  d_in[3];
  const float* embt = (const float*)d_in[4];
  const float* Wa   = (const float*)d_in[5];
  const float* Wih  = (const float*)d_in[6];
  const float* Whh  = (const float*)d_in[7];
  const float* bih  = (const float*)d_in[8];
  const float* bhh  = (const float*)d_in[9];
  float* out = (float*)d_out;

  char* p = (char*)d_ws;
  auto take = [&](size_t bytes) {
    char* q = p;
    p += (bytes + 255) & ~(size_t)255;
    return q;
  };
  short* ctx_hi = (short*)take((size_t)8388608 * 2);
  short* ctx_lo = (short*)take((size_t)8388608 * 2);
  short* BcH    = (short*)take((size_t)4096 * 2048 * 2);  // rows 0..3071 Wc, 3072+ Wa
  short* BcL    = (short*)take((size_t)4096 * 2048 * 2);
  short* We_p   = (short*)take((size_t)3072 * 512 * 2);
  short* WhH    = (short*)take((size_t)3072 * 1024 * 2);
  short* WhL    = (short*)take((size_t)3072 * 1024 * 2);
  float* bih_p  = (float*)take(3072 * 4);
  float* bhh_p  = (float*)take(3072 * 4);
  short* emb_bf = (short*)take((size_t)4096 * 512 * 2);
  float* Cc     = (float*)take((size_t)4096 * 4096 * 4);  // ctxWc | ctxW
  short* gxe    = (short*)take((size_t)4096 * 3072 * 2);
  float* hf     = (float*)take((size_t)65536 * 4);
  unsigned int* hpk = (unsigned int*)take((size_t)65536 * 4);
  float* attn   = (float*)take((size_t)4096 * 4);
  float* ghG    = (float*)take((size_t)3072 * 64 * 4);
  unsigned* bar = (unsigned*)take(8 * 4);

  // prologue
  split_bf16_kernel<<<2048, 256, 0, stream>>>(ctx, (__hip_bfloat16*)ctx_hi,
                                              (__hip_bfloat16*)ctx_lo, 8388608);
  split_bf16_kernel<<<1024, 256, 0, stream>>>(Wa,
      (__hip_bfloat16*)(BcH + (size_t)3072 * 2048),
      (__hip_bfloat16*)(BcL + (size_t)3072 * 2048), 2097152);
  prep_weights<<<3072, 256, 0, stream>>>(Wih, Whh, bih, bhh,
      (__hip_bfloat16*)BcH, (__hip_bfloat16*)BcL, (__hip_bfloat16*)We_p,
      (__hip_bfloat16*)WhH, (__hip_bfloat16*)WhL, bih_p, bhh_p);
  emb_gather<<<4096, 256, 0, stream>>>(tgt, embt, (__hip_bfloat16*)emb_bf);
  h0_init<<<256, 256, 0, stream>>>(h0, hf, hpk, bar);

  // Cc = ctx @ [Wc_perm; Wa]^T  (split-bf16 fused 3-product, fp32 out)
  gemm_bt3<<<dim3(32, 32), 256, 0, stream>>>(ctx_hi, ctx_lo, BcH, BcL,
                                             Cc, 4096, 4096, 2048);
  // gxe = emb @ We_perm^T + b_ih (bf16 out)
  gemm_bt<<<dim3(24, 32), 256, 0, stream>>>(emb_bf, We_p, nullptr,
                                            (__hip_bfloat16*)gxe, bih_p,
                                            4096, 3072, 512, FLAG_BF);

  // the whole 64-step recurrence in one persistent kernel
  rnn_loop<<<NBLK, 256, 0, stream>>>(Cc, lens, WhH, WhL,
      (const __hip_bfloat16*)gxe, bhh_p, hf, hpk, attn, ghG, out, bar);
}

// Round 7
// 5241.322 us; speedup vs baseline: 1.4698x; 1.0672x over previous
//
#include <hip/hip_runtime.h>
#include <hip/hip_bf16.h>

// DecoderRNNsearch on MI355X — round 7: round-6 structure with the hpkA
// index bug fixed (writer/reader agreed layout for MFMA-A-fragment packing).
//   idx(b,u) = (u>>5)*2048 + (b>>4)*512 + ((u>>3)&3)*128 + (b&15)*8 + (u&7)
// Everything else as round 6: persistent loop, relaxed-atomic barrier,
// per-access coherent ops for cross-block data, nontemporal loads/stores for
// single-use streams (ctxWc gather, gxe, out), batch-major phase B.

using short8 = __attribute__((ext_vector_type(8))) short;
using f32x4  = __attribute__((ext_vector_type(4))) float;

#define FLAG_ACC 1
#define FLAG_BF  2
#define NBLK 256

__device__ __forceinline__ void gld16(const void* g, void* l) {
  __builtin_amdgcn_global_load_lds(
      (const __attribute__((address_space(1))) unsigned int*)g,
      (__attribute__((address_space(3))) unsigned int*)l, 16, 0, 0);
}

// ---- per-access coherent (agent-scope, relaxed) helpers ----
__device__ __forceinline__ float cloadf(const float* p) {
  return __hip_atomic_load((float*)p, __ATOMIC_RELAXED, __HIP_MEMORY_SCOPE_AGENT);
}
__device__ __forceinline__ void cstoref(float* p, float v) {
  __hip_atomic_store(p, v, __ATOMIC_RELAXED, __HIP_MEMORY_SCOPE_AGENT);
}
__device__ __forceinline__ unsigned long long cload64(const void* p) {
  return __hip_atomic_load((unsigned long long*)p, __ATOMIC_RELAXED,
                           __HIP_MEMORY_SCOPE_AGENT);
}
__device__ __forceinline__ void cstoreu(unsigned int* p, unsigned int v) {
  __hip_atomic_store(p, v, __ATOMIC_RELAXED, __HIP_MEMORY_SCOPE_AGENT);
}

// ---- nontemporal helpers ----
__device__ __forceinline__ float ntloadf(const float* p) {
  return __builtin_nontemporal_load(p);
}
__device__ __forceinline__ float ntbf(const __hip_bfloat16* p) {
  unsigned short u = __builtin_nontemporal_load((const unsigned short*)p);
  union { float f; unsigned int i; } v; v.i = ((unsigned int)u) << 16;
  return v.f;
}

// ---- hpkA layout: MFMA-A-fragment order, shared by ALL writers/readers ----
// gh reader: lane-contiguous 8xu32 at c*2048 + w*512 + lane*8, lane = m + 16q,
// m = b&15 (wave w covers batches w*16..+15), k = c*32 + q*8 + j.
__device__ __forceinline__ size_t hpk_idx(int b, int u) {
  return ((size_t)(u >> 5) << 11) + ((size_t)(b >> 4) << 9) +
         ((size_t)((u >> 3) & 3) << 7) + ((size_t)(b & 15) << 3) + (u & 7);
}

// ---- grid barrier: monotonic relaxed counter ----
__device__ __forceinline__ void gbar(unsigned* cnt, unsigned target) {
  __syncthreads();
  if (threadIdx.x == 0) {
    __hip_atomic_fetch_add(cnt, 1u, __ATOMIC_RELAXED, __HIP_MEMORY_SCOPE_AGENT);
    while (__hip_atomic_load(cnt, __ATOMIC_RELAXED,
                             __HIP_MEMORY_SCOPE_AGENT) < target)
      __builtin_amdgcn_s_sleep(1);
  }
  __syncthreads();
}

// ---------------- conversion / prep kernels ----------------

__global__ __launch_bounds__(256) void split_bf16_kernel(
    const float* __restrict__ x, __hip_bfloat16* __restrict__ hi,
    __hip_bfloat16* __restrict__ lo, int n)
{
  int i = blockIdx.x * blockDim.x + threadIdx.x;
  int stride = gridDim.x * blockDim.x;
  for (; i < n; i += stride) {
    float v = x[i];
    __hip_bfloat16 h = __float2bfloat16(v);
    hi[i] = h;
    lo[i] = __float2bfloat16(v - __bfloat162float(h));
  }
}

// permute rows j' = 3u+g  <-  source row g*1024+u ; split to bf16 hi/lo.
__global__ __launch_bounds__(256) void prep_weights(
    const float* __restrict__ Wih, const float* __restrict__ Whh,
    const float* __restrict__ bih, const float* __restrict__ bhh,
    __hip_bfloat16* __restrict__ WcH, __hip_bfloat16* __restrict__ WcL,
    __hip_bfloat16* __restrict__ We,
    __hip_bfloat16* __restrict__ WhH, __hip_bfloat16* __restrict__ WhL,
    float* __restrict__ bihp, float* __restrict__ bhhp)
{
  const int jp = blockIdx.x;           // 0..3071
  const int u = jp / 3, g = jp - 3 * u;
  const int src = g * 1024 + u;
  for (int c = threadIdx.x; c < 2048; c += 256) {
    float v = Wih[(size_t)src * 2560 + 512 + c];
    __hip_bfloat16 h = __float2bfloat16(v);
    WcH[(size_t)jp * 2048 + c] = h;
    WcL[(size_t)jp * 2048 + c] = __float2bfloat16(v - __bfloat162float(h));
  }
  for (int c = threadIdx.x; c < 512; c += 256)
    We[(size_t)jp * 512 + c] = __float2bfloat16(Wih[(size_t)src * 2560 + c]);
  for (int c = threadIdx.x; c < 1024; c += 256) {
    float v = Whh[(size_t)src * 1024 + c];
    __hip_bfloat16 h = __float2bfloat16(v);
    WhH[(size_t)jp * 1024 + c] = h;
    WhL[(size_t)jp * 1024 + c] = __float2bfloat16(v - __bfloat162float(h));
  }
  if (threadIdx.x == 0) { bihp[jp] = bih[src]; bhhp[jp] = bhh[src]; }
}

__global__ __launch_bounds__(256) void emb_gather(
    const int* __restrict__ tgt, const float* __restrict__ table,
    __hip_bfloat16* __restrict__ outb)
{
  const int row = blockIdx.x;          // b*64+t, 0..4095
  const int v = tgt[row];
  for (int c = threadIdx.x; c < 512; c += 256)
    outb[(size_t)row * 512 + c] = __float2bfloat16(table[(size_t)v * 512 + c]);
}

__global__ __launch_bounds__(256) void h0_init(
    const float* __restrict__ h0, float* __restrict__ hf,
    unsigned int* __restrict__ hpkA, unsigned* __restrict__ bar)
{
  const int i = blockIdx.x * 256 + threadIdx.x;   // grid 256 -> 65536
  float v = h0[i];
  hf[i] = v;
  __hip_bfloat16 h = __float2bfloat16(v);
  __hip_bfloat16 l = __float2bfloat16(v - __bfloat162float(h));
  unsigned pk = (unsigned)*(unsigned short*)&h | ((unsigned)*(unsigned short*)&l << 16);
  const int b = i >> 10, k = i & 1023;
  hpkA[hpk_idx(b, k)] = pk;
  if (i < 8) bar[i] = 0u;
}

// ---------------- bf16 GEMM  C[M,N] = A[M,K] @ B[N,K]^T (single pass) -------

__global__ __launch_bounds__(256) void gemm_bt(
    const short* __restrict__ A, const short* __restrict__ B,
    float* __restrict__ Cf, __hip_bfloat16* __restrict__ Cb,
    const float* __restrict__ bias, int M, int N, int K, int flags)
{
  __shared__ __align__(16) short As[128 * 32];
  __shared__ __align__(16) short Bs[128 * 32];
  const int tid = threadIdx.x, lane = tid & 63, w = tid >> 6;
  const int m0 = blockIdx.y * 128, n0 = blockIdx.x * 128;
  const int wm = (w >> 1) * 64, wn = (w & 1) * 64;
  const int srow = lane >> 2, scol = (lane & 3) * 8;
  f32x4 zero = {0.f, 0.f, 0.f, 0.f};
  f32x4 acc[4][4];
#pragma unroll
  for (int i = 0; i < 4; ++i)
#pragma unroll
    for (int j = 0; j < 4; ++j) acc[i][j] = zero;

  for (int k0 = 0; k0 < K; k0 += 32) {
    __syncthreads();
#pragma unroll
    for (int s = 0; s < 2; ++s) {
      const int chunk = w * 2 + s;
      const int r = chunk * 16 + srow;
      gld16(A + (size_t)(m0 + r) * K + k0 + scol, As + chunk * 512);
      gld16(B + (size_t)(n0 + r) * K + k0 + scol, Bs + chunk * 512);
    }
    __syncthreads();
    const int fm = lane & 15, fq = lane >> 4;
    short8 af[4], bq[4];
#pragma unroll
    for (int i = 0; i < 4; ++i)
      af[i] = *(const short8*)(As + (wm + i * 16 + fm) * 32 + fq * 8);
#pragma unroll
    for (int j = 0; j < 4; ++j)
      bq[j] = *(const short8*)(Bs + (wn + j * 16 + fm) * 32 + fq * 8);
#pragma unroll
    for (int i = 0; i < 4; ++i)
#pragma unroll
      for (int j = 0; j < 4; ++j)
        acc[i][j] = __builtin_amdgcn_mfma_f32_16x16x32_bf16(af[i], bq[j], acc[i][j], 0, 0, 0);
  }

  const int cn = lane & 15, cq = (lane >> 4) * 4;
#pragma unroll
  for (int i = 0; i < 4; ++i)
#pragma unroll
    for (int j = 0; j < 4; ++j)
#pragma unroll
      for (int r = 0; r < 4; ++r) {
        const int m = m0 + wm + i * 16 + cq + r;
        const int n = n0 + wn + j * 16 + cn;
        float v = acc[i][j][r];
        if (flags & FLAG_ACC) v += Cf[(size_t)m * N + n];
        if (bias) v += bias[n];
        if (flags & FLAG_BF) Cb[(size_t)m * N + n] = __float2bfloat16(v);
        else                 Cf[(size_t)m * N + n] = v;
      }
}

// ---------------- fused split-bf16 triple GEMM --------------------------------

__global__ __launch_bounds__(256) void gemm_bt3(
    const short* __restrict__ AH, const short* __restrict__ AL,
    const short* __restrict__ BH, const short* __restrict__ BL,
    float* __restrict__ Cf, int M, int N, int K)
{
  __shared__ __align__(16) short AsH[128 * 32];
  __shared__ __align__(16) short AsL[128 * 32];
  __shared__ __align__(16) short BsH[128 * 32];
  __shared__ __align__(16) short BsL[128 * 32];
  const int tid = threadIdx.x, lane = tid & 63, w = tid >> 6;
  const int m0 = blockIdx.y * 128, n0 = blockIdx.x * 128;
  const int wm = (w >> 1) * 64, wn = (w & 1) * 64;
  const int srow = lane >> 2, scol = (lane & 3) * 8;
  f32x4 zero = {0.f, 0.f, 0.f, 0.f};
  f32x4 acc[4][4];
#pragma unroll
  for (int i = 0; i < 4; ++i)
#pragma unroll
    for (int j = 0; j < 4; ++j) acc[i][j] = zero;

  for (int k0 = 0; k0 < K; k0 += 32) {
    __syncthreads();
#pragma unroll
    for (int s = 0; s < 2; ++s) {
      const int chunk = w * 2 + s;
      const int r = chunk * 16 + srow;
      const size_t ao = (size_t)(m0 + r) * K + k0 + scol;
      const size_t bo = (size_t)(n0 + r) * K + k0 + scol;
      gld16(AH + ao, AsH + chunk * 512);
      gld16(AL + ao, AsL + chunk * 512);
      gld16(BH + bo, BsH + chunk * 512);
      gld16(BL + bo, BsL + chunk * 512);
    }
    __syncthreads();
    const int fm = lane & 15, fq = lane >> 4;
    short8 ah[4], al[4], bh[4], bl[4];
#pragma unroll
    for (int i = 0; i < 4; ++i) {
      const int off = (wm + i * 16 + fm) * 32 + fq * 8;
      ah[i] = *(const short8*)(AsH + off);
      al[i] = *(const short8*)(AsL + off);
    }
#pragma unroll
    for (int j = 0; j < 4; ++j) {
      const int off = (wn + j * 16 + fm) * 32 + fq * 8;
      bh[j] = *(const short8*)(BsH + off);
      bl[j] = *(const short8*)(BsL + off);
    }
#pragma unroll
    for (int i = 0; i < 4; ++i)
#pragma unroll
      for (int j = 0; j < 4; ++j) {
        acc[i][j] = __builtin_amdgcn_mfma_f32_16x16x32_bf16(ah[i], bh[j], acc[i][j], 0, 0, 0);
        acc[i][j] = __builtin_amdgcn_mfma_f32_16x16x32_bf16(al[i], bh[j], acc[i][j], 0, 0, 0);
        acc[i][j] = __builtin_amdgcn_mfma_f32_16x16x32_bf16(ah[i], bl[j], acc[i][j], 0, 0, 0);
      }
  }

  const int cn = lane & 15, cq = (lane >> 4) * 4;
#pragma unroll
  for (int i = 0; i < 4; ++i)
#pragma unroll
    for (int j = 0; j < 4; ++j)
#pragma unroll
      for (int r = 0; r < 4; ++r) {
        const int m = m0 + wm + i * 16 + cq + r;
        const int n = n0 + wn + j * 16 + cn;
        Cf[(size_t)m * N + n] = acc[i][j][r];
      }
}

// ---------------- THE persistent loop kernel ----------------------------------
// 256 blocks x 256 threads. Per step:
//   phase A: blocks 0..63 : attn batch b (coherent hf, cached ctxW rows)
//            blocks 64..95: gh = Whh@h split-bf16 3-pass MFMA, 96 j'-rows each,
//                           h from hpkA (A-fragment order, coalesced coherent),
//                           weights cached (L2-resident) -> ghT[b][j'] coherent
//   [gbar]
//   phase B: block (b = blk&63, jq = blk>>6): batch b, j-slice jq*768..+768.
//            wave-0 ballot compaction; nt contiguous Cc row reads; gates;
//            coherent h/hpkA stores; nt out/gxe.
//   [gbar]

__global__ __launch_bounds__(256, 1) void rnn_loop(
    const float* __restrict__ Cc,      // [4096][4096]: cols 0..3071 ctxWc, 3072+ ctxW
    const int* __restrict__ lens,
    const short* __restrict__ WhH, const short* __restrict__ WhL,
    const __hip_bfloat16* __restrict__ gxe, const float* __restrict__ bhhp,
    float* __restrict__ hf, unsigned int* __restrict__ hpkA,
    float* __restrict__ attnG, float* __restrict__ ghT,
    float* __restrict__ out, unsigned* __restrict__ bar)
{
  __shared__ union {
    struct { float hs[1024]; float part[256]; } a;
    struct { float wv[64]; short lidx[64]; int cnt; } b;
  } sm;

  const int blk = blockIdx.x, tid = threadIdx.x;
  const int lane = tid & 63, w = tid >> 6;
  const int fm = lane & 15, fq = lane >> 4;
  const f32x4 zero = {0.f, 0.f, 0.f, 0.f};
  unsigned bt = 0;

  for (int t = 0; t < 64; ++t) {
    // ---------------- phase A ----------------
    if (blk < 64) {
      const int b = blk;
      const int len = lens[b];
      {
        const unsigned long long* hp = (const unsigned long long*)(hf + b * 1024);
        unsigned long long v0 = cload64(hp + tid * 2);
        unsigned long long v1 = cload64(hp + tid * 2 + 1);
        float2 f0, f1;
        __builtin_memcpy(&f0, &v0, 8);
        __builtin_memcpy(&f1, &v1, 8);
        ((float2*)sm.a.hs)[tid * 2] = f0;
        ((float2*)sm.a.hs)[tid * 2 + 1] = f1;
      }
      __syncthreads();
      const int l = tid >> 2, q = tid & 3;
      float s = 0.f;
      if (l < len) {
        const float4* row =
            (const float4*)(Cc + (size_t)(b * 64 + l) * 4096 + 3072 + q * 256);
        const float4* hh = (const float4*)(sm.a.hs + q * 256);
#pragma unroll 8
        for (int i = 0; i < 64; ++i) {
          float4 a = row[i], c = hh[i];
          s += a.x * c.x + a.y * c.y + a.z * c.z + a.w * c.w;
        }
      }
      sm.a.part[tid] = s;
      __syncthreads();
      if (tid < 64) {   // wave 0; tid == context position
        float sc = sm.a.part[tid * 4] + sm.a.part[tid * 4 + 1] +
                   sm.a.part[tid * 4 + 2] + sm.a.part[tid * 4 + 3];
        if (tid >= len) sc = -1e9f;
        float m = sc;
#pragma unroll
        for (int off = 32; off > 0; off >>= 1) m = fmaxf(m, __shfl_xor(m, off));
        float e = __expf(sc - m);
        float sum = e;
#pragma unroll
        for (int off = 32; off > 0; off >>= 1) sum += __shfl_xor(sum, off);
        cstoref(&attnG[b * 64 + tid], e / sum);
      }
    } else if (blk < 96) {
      // gh: 96 j'-rows per block; h via hpkA (fragment-ordered, coalesced)
      const int j0 = (blk - 64) * 96;
      f32x4 acc[6];
#pragma unroll
      for (int g = 0; g < 6; ++g) acc[g] = zero;
#pragma unroll 2
      for (int c = 0; c < 32; ++c) {
        const unsigned long long* hq =
            (const unsigned long long*)(hpkA + c * 2048 + w * 512 + lane * 8);
        union { unsigned long long q[4]; unsigned int u[8]; } A_;
        A_.q[0] = cload64(hq + 0);
        A_.q[1] = cload64(hq + 1);
        A_.q[2] = cload64(hq + 2);
        A_.q[3] = cload64(hq + 3);
        union { unsigned int u[4]; short8 s; } H_, L_;
        H_.u[0] = __builtin_amdgcn_perm(A_.u[1], A_.u[0], 0x05040100u);
        H_.u[1] = __builtin_amdgcn_perm(A_.u[3], A_.u[2], 0x05040100u);
        H_.u[2] = __builtin_amdgcn_perm(A_.u[5], A_.u[4], 0x05040100u);
        H_.u[3] = __builtin_amdgcn_perm(A_.u[7], A_.u[6], 0x05040100u);
        L_.u[0] = __builtin_amdgcn_perm(A_.u[1], A_.u[0], 0x07060302u);
        L_.u[1] = __builtin_amdgcn_perm(A_.u[3], A_.u[2], 0x07060302u);
        L_.u[2] = __builtin_amdgcn_perm(A_.u[5], A_.u[4], 0x07060302u);
        L_.u[3] = __builtin_amdgcn_perm(A_.u[7], A_.u[6], 0x07060302u);
        const short8 aH = H_.s, aL = L_.s;
#pragma unroll
        for (int g = 0; g < 6; ++g) {
          const size_t boff = (size_t)(j0 + g * 16 + fm) * 1024 + fq * 8 + c * 32;
          short8 bh = *(const short8*)(WhH + boff);
          short8 bl = *(const short8*)(WhL + boff);
          acc[g] = __builtin_amdgcn_mfma_f32_16x16x32_bf16(aH, bh, acc[g], 0, 0, 0);
          acc[g] = __builtin_amdgcn_mfma_f32_16x16x32_bf16(aL, bh, acc[g], 0, 0, 0);
          acc[g] = __builtin_amdgcn_mfma_f32_16x16x32_bf16(aH, bl, acc[g], 0, 0, 0);
        }
      }
      // C: batch m = w*16 + fq*4 + r, col j' = j0 + g*16 + fm -> ghT[m][j']
      const int mb = w * 16 + fq * 4;
#pragma unroll
      for (int g = 0; g < 6; ++g)
#pragma unroll
        for (int r = 0; r < 4; ++r)
          cstoref(ghT + (size_t)(mb + r) * 3072 + j0 + g * 16 + fm, acc[g][r]);
    }
    bt += NBLK;
    gbar(bar, bt);

    // ---------------- phase B: gates (batch-major) ----------------
    {
      const int b = blk & 63, jq = blk >> 6;
      const int j0 = jq * 768;
      if (tid < 64) {   // wave 0: ballot compaction (deterministic, ascending l)
        const int len = lens[b];
        float wl = cloadf(&attnG[b * 64 + tid]);
        bool pred = (tid < len) && (wl >= 1e-8f);
        unsigned long long mask = __ballot(pred);
        if (pred) {
          int pos = __popcll(mask & ((1ull << tid) - 1ull));
          sm.b.lidx[pos] = (short)tid;
          sm.b.wv[pos] = wl;
        }
        if (tid == 0) sm.b.cnt = (int)__popcll(mask);
      }
      __syncthreads();
      const int n = sm.b.cnt;
      const int jp = j0 + tid * 3;          // this thread's 3 gate rows
      float g0 = 0.f, g1 = 0.f, g2 = 0.f;
      const float* base = Cc + (size_t)(b * 64) * 4096 + jp;
      int i = 0;
      for (; i + 1 < n; i += 2) {
        const float wa = sm.b.wv[i], wb2 = sm.b.wv[i + 1];
        const float* pa = base + (size_t)sm.b.lidx[i] * 4096;
        const float* pb = base + (size_t)sm.b.lidx[i + 1] * 4096;
        const float a0 = ntloadf(pa + 0), a1 = ntloadf(pa + 1), a2 = ntloadf(pa + 2);
        const float c0 = ntloadf(pb + 0), c1 = ntloadf(pb + 1), c2 = ntloadf(pb + 2);
        g0 += wa * a0 + wb2 * c0;
        g1 += wa * a1 + wb2 * c1;
        g2 += wa * a2 + wb2 * c2;
      }
      if (i < n) {
        const float wa = sm.b.wv[i];
        const float* pa = base + (size_t)sm.b.lidx[i] * 4096;
        g0 += wa * ntloadf(pa + 0);
        g1 += wa * ntloadf(pa + 1);
        g2 += wa * ntloadf(pa + 2);
      }

      const __hip_bfloat16* ge = gxe + (size_t)(b * 64 + t) * 3072 + jp;
      const float gxr = g0 + ntbf(ge + 0);
      const float gxz = g1 + ntbf(ge + 1);
      const float gxn = g2 + ntbf(ge + 2);
      const float* gh = ghT + (size_t)b * 3072 + jp;
      const float ghr = cloadf(gh + 0) + bhhp[jp + 0];
      const float ghz = cloadf(gh + 1) + bhhp[jp + 1];
      const float ghn = cloadf(gh + 2) + bhhp[jp + 2];
      const float rr = 1.f / (1.f + __expf(-(gxr + ghr)));
      const float zz = 1.f / (1.f + __expf(-(gxz + ghz)));
      const float nn = tanhf(gxn + rr * ghn);
      const int u = jq * 256 + tid;
      const float hold = cloadf(&hf[b * 1024 + u]);
      const float hn = (1.f - zz) * nn + zz * hold;
      __builtin_nontemporal_store(hn, out + (size_t)(b * 64 + t) * 1024 + u);
      cstoref(&hf[b * 1024 + u], hn);
      __hip_bfloat16 hh = __float2bfloat16(hn);
      __hip_bfloat16 hl = __float2bfloat16(hn - __bfloat162float(hh));
      unsigned int pk = (unsigned)*(unsigned short*)&hh |
                        ((unsigned)*(unsigned short*)&hl << 16);
      cstoreu(&hpkA[hpk_idx(b, u)], pk);
      if (t == 63)
        __builtin_nontemporal_store(hn, out + (size_t)64 * 64 * 1024 + b * 1024 + u);
    }
    bt += NBLK;
    gbar(bar, bt);
  }
}

// ---------------- launcher ----------------

extern "C" void kernel_launch(void* const* d_in, const int* in_sizes, int n_in,
                              void* d_out, int out_size, void* d_ws, size_t ws_size,
                              hipStream_t stream)
{
  const int*   tgt  = (const int*)  d_in[0];
  const float* ctx  = (const float*)d_in[1];
  const float* h0   = (const float*)d_in[2];
  const int*   lens = (const int*)  d_in[3];
  const float* embt = (const float*)d_in[4];
  const float* Wa   = (const float*)d_in[5];
  const float* Wih  = (const float*)d_in[6];
  const float* Whh  = (const float*)d_in[7];
  const float* bih  = (const float*)d_in[8];
  const float* bhh  = (const float*)d_in[9];
  float* out = (float*)d_out;

  char* p = (char*)d_ws;
  auto take = [&](size_t bytes) {
    char* q = p;
    p += (bytes + 255) & ~(size_t)255;
    return q;
  };
  short* ctx_hi = (short*)take((size_t)8388608 * 2);
  short* ctx_lo = (short*)take((size_t)8388608 * 2);
  short* BcH    = (short*)take((size_t)4096 * 2048 * 2);  // rows 0..3071 Wc, 3072+ Wa
  short* BcL    = (short*)take((size_t)4096 * 2048 * 2);
  short* We_p   = (short*)take((size_t)3072 * 512 * 2);
  short* WhH    = (short*)take((size_t)3072 * 1024 * 2);
  short* WhL    = (short*)take((size_t)3072 * 1024 * 2);
  float* bih_p  = (float*)take(3072 * 4);
  float* bhh_p  = (float*)take(3072 * 4);
  short* emb_bf = (short*)take((size_t)4096 * 512 * 2);
  float* Cc     = (float*)take((size_t)4096 * 4096 * 4);  // ctxWc | ctxW
  short* gxe    = (short*)take((size_t)4096 * 3072 * 2);
  float* hf     = (float*)take((size_t)65536 * 4);
  unsigned int* hpkA = (unsigned int*)take((size_t)65536 * 4);
  float* attn   = (float*)take((size_t)4096 * 4);
  float* ghT    = (float*)take((size_t)64 * 3072 * 4);
  unsigned* bar = (unsigned*)take(8 * 4);

  // prologue
  split_bf16_kernel<<<2048, 256, 0, stream>>>(ctx, (__hip_bfloat16*)ctx_hi,
                                              (__hip_bfloat16*)ctx_lo, 8388608);
  split_bf16_kernel<<<1024, 256, 0, stream>>>(Wa,
      (__hip_bfloat16*)(BcH + (size_t)3072 * 2048),
      (__hip_bfloat16*)(BcL + (size_t)3072 * 2048), 2097152);
  prep_weights<<<3072, 256, 0, stream>>>(Wih, Whh, bih, bhh,
      (__hip_bfloat16*)BcH, (__hip_bfloat16*)BcL, (__hip_bfloat16*)We_p,
      (__hip_bfloat16*)WhH, (__hip_bfloat16*)WhL, bih_p, bhh_p);
  emb_gather<<<4096, 256, 0, stream>>>(tgt, embt, (__hip_bfloat16*)emb_bf);
  h0_init<<<256, 256, 0, stream>>>(h0, hf, hpkA, bar);

  // Cc = ctx @ [Wc_perm; Wa]^T  (split-bf16 fused 3-product, fp32 out)
  gemm_bt3<<<dim3(32, 32), 256, 0, stream>>>(ctx_hi, ctx_lo, BcH, BcL,
                                             Cc, 4096, 4096, 2048);
  // gxe = emb @ We_perm^T + b_ih (bf16 out)
  gemm_bt<<<dim3(24, 32), 256, 0, stream>>>(emb_bf, We_p, nullptr,
                                            (__hip_bfloat16*)gxe, bih_p,
                                            4096, 3072, 512, FLAG_BF);

  // the whole 64-step recurrence in one persistent kernel
  rnn_loop<<<NBLK, 256, 0, stream>>>(Cc, lens, WhH, WhL,
      (const __hip_bfloat16*)gxe, bhh_p, hf, hpkA, attn, ghT, out, bar);
}